// Round 1
// baseline (646.130 us; speedup 1.0000x reference)
//
#include <hip/hip_runtime.h>
#include <cstdint>
#include <cstddef>

// Problem constants (fixed by the reference)
#define BB 4
#define TT 2048
#define DDIM 1024
#define KCODES 8192
#define MROWS (BB*TT)          // 8192

typedef _Float16 f16;
typedef _Float16 half8 __attribute__((ext_vector_type(8)));
typedef _Float16 half4v __attribute__((ext_vector_type(4)));
typedef float f32x4 __attribute__((ext_vector_type(4)));

// ---- helpers -------------------------------------------------------------

// monotonic float->uint mapping, packed with index: min(packed) == (min score, lowest idx)
__device__ __forceinline__ unsigned long long packScore(float s, unsigned int idx){
  unsigned int b = __float_as_uint(s);
  b ^= (b & 0x80000000u) ? 0xFFFFFFFFu : 0x80000000u;
  return ((unsigned long long)b << 32) | (unsigned long long)idx;
}

__device__ __forceinline__ unsigned long long shflxor64(unsigned long long v, int m){
  unsigned int lo = (unsigned int)v;
  unsigned int hi = (unsigned int)(v >> 32);
  lo = __shfl_xor(lo, m, 64);
  hi = __shfl_xor(hi, m, 64);
  return ((unsigned long long)hi << 32) | lo;
}

// async global->LDS, 16B per lane; lds base must be wave-uniform (HW writes lane l at +16*l)
__device__ __forceinline__ void glds16(const void* g, void* l){
  __builtin_amdgcn_global_load_lds(
      (const __attribute__((address_space(1))) unsigned int*)g,
      (__attribute__((address_space(3))) unsigned int*)l, 16, 0, 0);
}

// ---- prep kernels --------------------------------------------------------

__global__ void init_packed(unsigned long long* p){
  p[blockIdx.x * 256 + threadIdx.x] = ~0ull;
}

// x row -> f16 hi + f16 residual lo (exact split: lo = x - (f32)hi, then f16-rounded)
__global__ void prep_x(const float* __restrict__ x, f16* __restrict__ Ahi, f16* __restrict__ Alo){
  const int row = blockIdx.x;
  const int tid = threadIdx.x;
  const float4 v = ((const float4*)x)[(size_t)row * 256 + tid];
  float vv[4] = {v.x, v.y, v.z, v.w};
  half4v hi, lo;
  #pragma unroll
  for (int j = 0; j < 4; ++j){
    f16 h = (f16)vv[j];
    hi[j] = h;
    lo[j] = (f16)(vv[j] - (float)h);
  }
  ((half4v*)Ahi)[(size_t)row * 256 + tid] = hi;
  ((half4v*)Alo)[(size_t)row * 256 + tid] = lo;
}

// codebook row -> hi/lo split + exact fp32 ||c||^2
__global__ void prep_cb(const float* __restrict__ cb, f16* __restrict__ Bhi,
                        f16* __restrict__ Blo, float* __restrict__ csq){
  const int row = blockIdx.x;
  const int tid = threadIdx.x;
  const float4 v = ((const float4*)cb)[(size_t)row * 256 + tid];
  float vv[4] = {v.x, v.y, v.z, v.w};
  half4v hi, lo;
  float s = 0.f;
  #pragma unroll
  for (int j = 0; j < 4; ++j){
    f16 h = (f16)vv[j];
    hi[j] = h;
    lo[j] = (f16)(vv[j] - (float)h);
    s += vv[j] * vv[j];
  }
  ((half4v*)Bhi)[(size_t)row * 256 + tid] = hi;
  ((half4v*)Blo)[(size_t)row * 256 + tid] = lo;
  #pragma unroll
  for (int m = 32; m; m >>= 1) s += __shfl_xor(s, m, 64);
  __shared__ float red[4];
  if ((tid & 63) == 0) red[tid >> 6] = s;
  __syncthreads();
  if (tid == 0) csq[row] = red[0] + red[1] + red[2] + red[3];
}

// ---- main GEMM + argmin kernel ------------------------------------------
// 128x128 tile, BK=64, 4 waves (2x2), each wave 64x64 via 4x4 frags of 16x16x32 f16 MFMA.
// Inner dim is logically 3072: seg0 = Ahi*Bhi, seg1 = Ahi*Blo, seg2 = Alo*Bhi.
// Epilogue: score = csq[col] - 2*acc, per-row packed argmin -> global atomicMin.
__global__ __launch_bounds__(256) void vq_gemm(
    const f16* __restrict__ Ahi, const f16* __restrict__ Alo,
    const f16* __restrict__ Bhi, const f16* __restrict__ Blo,
    const float* __restrict__ csq, unsigned long long* __restrict__ packed)
{
  __shared__ f16 sA[128 * 64];
  __shared__ f16 sB[128 * 64];
  const int tid  = threadIdx.x;
  const int lane = tid & 63;
  const int wid  = tid >> 6;
  const int wm   = wid >> 1, wn = wid & 1;
  const int bm   = blockIdx.y, bn = blockIdx.x;
  const int l15  = lane & 15, lk = lane >> 4;

  f32x4 acc[4][4];
  #pragma unroll
  for (int i = 0; i < 4; ++i)
    #pragma unroll
    for (int j = 0; j < 4; ++j)
      acc[i][j] = (f32x4)0.0f;

  const int stage_row = lane >> 3;        // 0..7 within an 8-row/1KB issue
  const int stage_col = (lane & 7) * 8;   // halves

  for (int kt = 0; kt < 48; ++kt){
    const int seg = kt >> 4;              // 0: hi*hi, 1: hi*lo, 2: lo*hi
    const int kin = (kt & 15) * 64;       // column within the 1024-wide segment
    const f16* Ap = (seg == 2) ? Alo : Ahi;
    const f16* Bp = (seg == 1) ? Blo : Bhi;

    __syncthreads();  // previous compute done before LDS overwrite
    #pragma unroll
    for (int i = 0; i < 4; ++i){
      const int r = wid * 32 + i * 8 + stage_row;
      glds16(Ap + ((size_t)(bm * 128 + r)) * DDIM + kin + stage_col,
             sA + (wid * 32 + i * 8) * 64);
      glds16(Bp + ((size_t)(bn * 128 + r)) * DDIM + kin + stage_col,
             sB + (wid * 32 + i * 8) * 64);
    }
    __syncthreads();  // staging visible (compiler drains vmcnt before s_barrier)

    #pragma unroll
    for (int kk = 0; kk < 2; ++kk){
      half8 a[4], b[4];
      #pragma unroll
      for (int mf = 0; mf < 4; ++mf)
        a[mf] = *(const half8*)&sA[(wm * 64 + mf * 16 + l15) * 64 + kk * 32 + lk * 8];
      #pragma unroll
      for (int nf = 0; nf < 4; ++nf)
        b[nf] = *(const half8*)&sB[(wn * 64 + nf * 16 + l15) * 64 + kk * 32 + lk * 8];
      #pragma unroll
      for (int mf = 0; mf < 4; ++mf)
        #pragma unroll
        for (int nf = 0; nf < 4; ++nf)
          acc[mf][nf] = __builtin_amdgcn_mfma_f32_16x16x32_f16(a[mf], b[nf], acc[mf][nf], 0, 0, 0);
    }
  }

  // epilogue: per-row argmin over this block's 128 cols
  float csqv[4];
  unsigned int gcolv[4];
  #pragma unroll
  for (int nf = 0; nf < 4; ++nf){
    gcolv[nf] = bn * 128 + wn * 64 + nf * 16 + l15;
    csqv[nf]  = csq[gcolv[nf]];
  }
  #pragma unroll
  for (int mf = 0; mf < 4; ++mf){
    #pragma unroll
    for (int r = 0; r < 4; ++r){
      const int grow = bm * 128 + wm * 64 + mf * 16 + lk * 4 + r;
      unsigned long long best = ~0ull;
      #pragma unroll
      for (int nf = 0; nf < 4; ++nf){
        unsigned long long p = packScore(csqv[nf] - 2.0f * acc[mf][nf][r], gcolv[nf]);
        best = (p < best) ? p : best;
      }
      #pragma unroll
      for (int m = 1; m < 16; m <<= 1){
        unsigned long long o = shflxor64(best, m);
        best = (o < best) ? o : best;
      }
      if (l15 == 0) atomicMin(&packed[grow], best);
    }
  }
}

// ---- gather: out[row] = emb[idx[row]] + pe[row % T] ----------------------
__global__ void vq_gather(const unsigned long long* __restrict__ packed,
                          const float* __restrict__ emb, const float* __restrict__ pe,
                          float* __restrict__ out){
  const int row = blockIdx.x, tid = threadIdx.x;
  const unsigned int idx = (unsigned int)(packed[row] & 0xFFFFFFFFu);
  const int t = row & (TT - 1);
  const float4 e = ((const float4*)emb)[(size_t)idx * 256 + tid];
  const float4 p = ((const float4*)pe)[(size_t)t * 256 + tid];
  float4 o;
  o.x = e.x + p.x; o.y = e.y + p.y; o.z = e.z + p.z; o.w = e.w + p.w;
  ((float4*)out)[(size_t)row * 256 + tid] = o;
}

// ---- exact fp32 fallback (no workspace needed; slow but correct) ---------
__global__ void vq_fallback(const float* __restrict__ x, const float* __restrict__ cb,
                            const float* __restrict__ emb, const float* __restrict__ pe,
                            float* __restrict__ out){
  __shared__ float4 xs[256];
  __shared__ unsigned long long red[256];
  const int row = blockIdx.x, tid = threadIdx.x;
  xs[tid] = ((const float4*)x)[(size_t)row * 256 + tid];
  __syncthreads();
  unsigned long long best = ~0ull;
  for (int k = tid; k < KCODES; k += 256){
    const float4* c4 = (const float4*)(cb + (size_t)k * DDIM);
    float dot = 0.f, cs = 0.f;
    for (int j = 0; j < 256; ++j){
      float4 c = c4[j], xv = xs[j];
      dot += c.x * xv.x + c.y * xv.y + c.z * xv.z + c.w * xv.w;
      cs  += c.x * c.x + c.y * c.y + c.z * c.z + c.w * c.w;
    }
    unsigned long long p = packScore(cs - 2.f * dot, (unsigned)k);
    best = (p < best) ? p : best;
  }
  red[tid] = best;
  __syncthreads();
  for (int s = 128; s; s >>= 1){
    if (tid < s && red[tid + s] < red[tid]) red[tid] = red[tid + s];
    __syncthreads();
  }
  const unsigned int idx = (unsigned int)(red[0] & 0xFFFFFFFFu);
  const int t = row & (TT - 1);
  const float4 e = ((const float4*)emb)[(size_t)idx * 256 + tid];
  const float4 p = ((const float4*)pe)[(size_t)t * 256 + tid];
  float4 o;
  o.x = e.x + p.x; o.y = e.y + p.y; o.z = e.z + p.z; o.w = e.w + p.w;
  ((float4*)out)[(size_t)row * 256 + tid] = o;
}

// ---- launch --------------------------------------------------------------
extern "C" void kernel_launch(void* const* d_in, const int* in_sizes, int n_in,
                              void* d_out, int out_size, void* d_ws, size_t ws_size,
                              hipStream_t stream){
  const float* x   = (const float*)d_in[0];
  const float* cb  = (const float*)d_in[1];
  const float* emb = (const float*)d_in[2];
  const float* pe  = (const float*)d_in[3];
  float* out = (float*)d_out;

  const size_t OFF_PACKED = 0;                       // 8192 * 8 B = 64 KB
  const size_t OFF_CSQ    = 65536;                   // 8192 * 4 B = 32 KB
  const size_t OFF_A      = 131072;
  const size_t SEG        = (size_t)MROWS * DDIM * sizeof(f16);  // 16 MB each
  const size_t NEEDED     = OFF_A + 4 * SEG;         // ~64.1 MB

  if (ws_size >= NEEDED){
    unsigned long long* packed = (unsigned long long*)((char*)d_ws + OFF_PACKED);
    float* csq = (float*)((char*)d_ws + OFF_CSQ);
    f16* Ahi = (f16*)((char*)d_ws + OFF_A);
    f16* Alo = Ahi + (size_t)MROWS * DDIM;
    f16* Bhi = Alo + (size_t)MROWS * DDIM;
    f16* Blo = Bhi + (size_t)KCODES * DDIM;

    hipLaunchKernelGGL(init_packed, dim3(32), dim3(256), 0, stream, packed);
    hipLaunchKernelGGL(prep_x,  dim3(MROWS),  dim3(256), 0, stream, x,  Ahi, Alo);
    hipLaunchKernelGGL(prep_cb, dim3(KCODES), dim3(256), 0, stream, cb, Bhi, Blo, csq);
    hipLaunchKernelGGL(vq_gemm, dim3(64, 64), dim3(256), 0, stream,
                       Ahi, Alo, Bhi, Blo, csq, packed);
    hipLaunchKernelGGL(vq_gather, dim3(MROWS), dim3(256), 0, stream, packed, emb, pe, out);
  } else {
    hipLaunchKernelGGL(vq_fallback, dim3(MROWS), dim3(256), 0, stream, x, cb, emb, pe, out);
  }
}

// Round 2
// 492.033 us; speedup vs baseline: 1.3132x; 1.3132x over previous
//
#include <hip/hip_runtime.h>
#include <cstdint>
#include <cstddef>

// Problem constants (fixed by the reference)
#define BB 4
#define TT 2048
#define DDIM 1024
#define KCODES 8192
#define MROWS (BB*TT)          // 8192

typedef _Float16 f16;
typedef _Float16 half8 __attribute__((ext_vector_type(8)));
typedef _Float16 half4v __attribute__((ext_vector_type(4)));
typedef float f32x4 __attribute__((ext_vector_type(4)));

// ---- helpers -------------------------------------------------------------

// monotonic float->uint mapping, packed with index: min(packed) == (min score, lowest idx)
__device__ __forceinline__ unsigned long long packScore(float s, unsigned int idx){
  unsigned int b = __float_as_uint(s);
  b ^= (b & 0x80000000u) ? 0xFFFFFFFFu : 0x80000000u;
  return ((unsigned long long)b << 32) | (unsigned long long)idx;
}

__device__ __forceinline__ unsigned long long shflxor64(unsigned long long v, int m){
  unsigned int lo = (unsigned int)v;
  unsigned int hi = (unsigned int)(v >> 32);
  lo = __shfl_xor(lo, m, 64);
  hi = __shfl_xor(hi, m, 64);
  return ((unsigned long long)hi << 32) | lo;
}

// async global->LDS, 16B per lane; lds base must be wave-uniform (HW writes lane l at +16*l)
__device__ __forceinline__ void glds16(const void* g, void* l){
  __builtin_amdgcn_global_load_lds(
      (const __attribute__((address_space(1))) unsigned int*)g,
      (__attribute__((address_space(3))) unsigned int*)l, 16, 0, 0);
}

// ---- prep kernels --------------------------------------------------------

__global__ void init_packed(unsigned long long* p){
  p[blockIdx.x * 256 + threadIdx.x] = ~0ull;
}

// x row -> f16 hi + f16 residual lo (exact split: lo = x - (f32)hi, then f16-rounded)
__global__ void prep_x(const float* __restrict__ x, f16* __restrict__ Ahi, f16* __restrict__ Alo){
  const int row = blockIdx.x;
  const int tid = threadIdx.x;
  const float4 v = ((const float4*)x)[(size_t)row * 256 + tid];
  float vv[4] = {v.x, v.y, v.z, v.w};
  half4v hi, lo;
  #pragma unroll
  for (int j = 0; j < 4; ++j){
    f16 h = (f16)vv[j];
    hi[j] = h;
    lo[j] = (f16)(vv[j] - (float)h);
  }
  ((half4v*)Ahi)[(size_t)row * 256 + tid] = hi;
  ((half4v*)Alo)[(size_t)row * 256 + tid] = lo;
}

// codebook row -> hi/lo split + exact fp32 ||c||^2
__global__ void prep_cb(const float* __restrict__ cb, f16* __restrict__ Bhi,
                        f16* __restrict__ Blo, float* __restrict__ csq){
  const int row = blockIdx.x;
  const int tid = threadIdx.x;
  const float4 v = ((const float4*)cb)[(size_t)row * 256 + tid];
  float vv[4] = {v.x, v.y, v.z, v.w};
  half4v hi, lo;
  float s = 0.f;
  #pragma unroll
  for (int j = 0; j < 4; ++j){
    f16 h = (f16)vv[j];
    hi[j] = h;
    lo[j] = (f16)(vv[j] - (float)h);
    s += vv[j] * vv[j];
  }
  ((half4v*)Bhi)[(size_t)row * 256 + tid] = hi;
  ((half4v*)Blo)[(size_t)row * 256 + tid] = lo;
  #pragma unroll
  for (int m = 32; m; m >>= 1) s += __shfl_xor(s, m, 64);
  __shared__ float red[4];
  if ((tid & 63) == 0) red[tid >> 6] = s;
  __syncthreads();
  if (tid == 0) csq[row] = red[0] + red[1] + red[2] + red[3];
}

// ---- main GEMM + argmin kernel ------------------------------------------
// 128x128 tile, BK=64, 4 waves (2x2), each wave 64x64 via 4x4 frags of 16x16x32 f16 MFMA.
// Inner dim is logically 3072: seg0 = Ahi*Bhi, seg1 = Ahi*Blo, seg2 = Alo*Bhi.
// LDS layout: each 128B row holds 8 physical 16B slots; data for logical slot s
// of row r lives at physical slot s ^ (r&7)  (T2 XOR swizzle, both sides:
// pre-swizzled global source for the linear global_load_lds write, swizzled
// ds_read address on the fragment load). Kills the 16-way bank conflict.
__global__ __launch_bounds__(256) void vq_gemm(
    const f16* __restrict__ Ahi, const f16* __restrict__ Alo,
    const f16* __restrict__ Bhi, const f16* __restrict__ Blo,
    const float* __restrict__ csq, unsigned long long* __restrict__ packed)
{
  __shared__ f16 sA[128 * 64];
  __shared__ f16 sB[128 * 64];
  const int tid  = threadIdx.x;
  const int lane = tid & 63;
  const int wid  = tid >> 6;
  const int wm   = wid >> 1, wn = wid & 1;
  const int bm   = blockIdx.y, bn = blockIdx.x;
  const int l15  = lane & 15, lk = lane >> 4;

  f32x4 acc[4][4];
  #pragma unroll
  for (int i = 0; i < 4; ++i)
    #pragma unroll
    for (int j = 0; j < 4; ++j)
      acc[i][j] = (f32x4)0.0f;

  // staging geometry: one glds16 covers 8 rows x 128B; lane l -> row l>>3,
  // physical slot l&7. Pre-swizzle the GLOBAL column so physical slot p
  // receives logical slot p ^ (row&7):
  const int stage_row = lane >> 3;                       // 0..7
  const int stage_col = (((lane & 7) ^ stage_row) * 8);  // halves, swizzled source

  for (int kt = 0; kt < 48; ++kt){
    const int seg = kt >> 4;              // 0: hi*hi, 1: hi*lo, 2: lo*hi
    const int kin = (kt & 15) * 64;       // column within the 1024-wide segment
    const f16* Ap = (seg == 2) ? Alo : Ahi;
    const f16* Bp = (seg == 1) ? Blo : Bhi;

    __syncthreads();  // previous compute done before LDS overwrite
    #pragma unroll
    for (int i = 0; i < 4; ++i){
      const int r = wid * 32 + i * 8 + stage_row;
      glds16(Ap + ((size_t)(bm * 128 + r)) * DDIM + kin + stage_col,
             sA + (wid * 32 + i * 8) * 64);
      glds16(Bp + ((size_t)(bn * 128 + r)) * DDIM + kin + stage_col,
             sB + (wid * 32 + i * 8) * 64);
    }
    __syncthreads();  // staging visible (compiler drains vmcnt before s_barrier)

    #pragma unroll
    for (int kk = 0; kk < 2; ++kk){
      half8 a[4], b[4];
      #pragma unroll
      for (int mf = 0; mf < 4; ++mf){
        const int r = wm * 64 + mf * 16 + l15;
        const int p = (kk * 4 + lk) ^ (r & 7);           // swizzled read slot
        a[mf] = *(const half8*)&sA[r * 64 + p * 8];
      }
      #pragma unroll
      for (int nf = 0; nf < 4; ++nf){
        const int r = wn * 64 + nf * 16 + l15;
        const int p = (kk * 4 + lk) ^ (r & 7);
        b[nf] = *(const half8*)&sB[r * 64 + p * 8];
      }
      #pragma unroll
      for (int mf = 0; mf < 4; ++mf)
        #pragma unroll
        for (int nf = 0; nf < 4; ++nf)
          acc[mf][nf] = __builtin_amdgcn_mfma_f32_16x16x32_f16(a[mf], b[nf], acc[mf][nf], 0, 0, 0);
    }
  }

  // epilogue: per-row argmin over this block's 128 cols
  float csqv[4];
  unsigned int gcolv[4];
  #pragma unroll
  for (int nf = 0; nf < 4; ++nf){
    gcolv[nf] = bn * 128 + wn * 64 + nf * 16 + l15;
    csqv[nf]  = csq[gcolv[nf]];
  }
  #pragma unroll
  for (int mf = 0; mf < 4; ++mf){
    #pragma unroll
    for (int r = 0; r < 4; ++r){
      const int grow = bm * 128 + wm * 64 + mf * 16 + lk * 4 + r;
      unsigned long long best = ~0ull;
      #pragma unroll
      for (int nf = 0; nf < 4; ++nf){
        unsigned long long p = packScore(csqv[nf] - 2.0f * acc[mf][nf][r], gcolv[nf]);
        best = (p < best) ? p : best;
      }
      #pragma unroll
      for (int m = 1; m < 16; m <<= 1){
        unsigned long long o = shflxor64(best, m);
        best = (o < best) ? o : best;
      }
      if (l15 == 0) atomicMin(&packed[grow], best);
    }
  }
}

// ---- gather: out[row] = emb[idx[row]] + pe[row % T] ----------------------
__global__ void vq_gather(const unsigned long long* __restrict__ packed,
                          const float* __restrict__ emb, const float* __restrict__ pe,
                          float* __restrict__ out){
  const int row = blockIdx.x, tid = threadIdx.x;
  const unsigned int idx = (unsigned int)(packed[row] & 0xFFFFFFFFu);
  const int t = row & (TT - 1);
  const float4 e = ((const float4*)emb)[(size_t)idx * 256 + tid];
  const float4 p = ((const float4*)pe)[(size_t)t * 256 + tid];
  float4 o;
  o.x = e.x + p.x; o.y = e.y + p.y; o.z = e.z + p.z; o.w = e.w + p.w;
  ((float4*)out)[(size_t)row * 256 + tid] = o;
}

// ---- exact fp32 fallback (no workspace needed; slow but correct) ---------
__global__ void vq_fallback(const float* __restrict__ x, const float* __restrict__ cb,
                            const float* __restrict__ emb, const float* __restrict__ pe,
                            float* __restrict__ out){
  __shared__ float4 xs[256];
  __shared__ unsigned long long red[256];
  const int row = blockIdx.x, tid = threadIdx.x;
  xs[tid] = ((const float4*)x)[(size_t)row * 256 + tid];
  __syncthreads();
  unsigned long long best = ~0ull;
  for (int k = tid; k < KCODES; k += 256){
    const float4* c4 = (const float4*)(cb + (size_t)k * DDIM);
    float dot = 0.f, cs = 0.f;
    for (int j = 0; j < 256; ++j){
      float4 c = c4[j], xv = xs[j];
      dot += c.x * xv.x + c.y * xv.y + c.z * xv.z + c.w * xv.w;
      cs  += c.x * c.x + c.y * c.y + c.z * c.z + c.w * c.w;
    }
    unsigned long long p = packScore(cs - 2.f * dot, (unsigned)k);
    best = (p < best) ? p : best;
  }
  red[tid] = best;
  __syncthreads();
  for (int s = 128; s; s >>= 1){
    if (tid < s && red[tid + s] < red[tid]) red[tid] = red[tid + s];
    __syncthreads();
  }
  const unsigned int idx = (unsigned int)(red[0] & 0xFFFFFFFFu);
  const int t = row & (TT - 1);
  const float4 e = ((const float4*)emb)[(size_t)idx * 256 + tid];
  const float4 p = ((const float4*)pe)[(size_t)t * 256 + tid];
  float4 o;
  o.x = e.x + p.x; o.y = e.y + p.y; o.z = e.z + p.z; o.w = e.w + p.w;
  ((float4*)out)[(size_t)row * 256 + tid] = o;
}

// ---- launch --------------------------------------------------------------
extern "C" void kernel_launch(void* const* d_in, const int* in_sizes, int n_in,
                              void* d_out, int out_size, void* d_ws, size_t ws_size,
                              hipStream_t stream){
  const float* x   = (const float*)d_in[0];
  const float* cb  = (const float*)d_in[1];
  const float* emb = (const float*)d_in[2];
  const float* pe  = (const float*)d_in[3];
  float* out = (float*)d_out;

  const size_t OFF_PACKED = 0;                       // 8192 * 8 B = 64 KB
  const size_t OFF_CSQ    = 65536;                   // 8192 * 4 B = 32 KB
  const size_t OFF_A      = 131072;
  const size_t SEG        = (size_t)MROWS * DDIM * sizeof(f16);  // 16 MB each
  const size_t NEEDED     = OFF_A + 4 * SEG;         // ~64.1 MB

  if (ws_size >= NEEDED){
    unsigned long long* packed = (unsigned long long*)((char*)d_ws + OFF_PACKED);
    float* csq = (float*)((char*)d_ws + OFF_CSQ);
    f16* Ahi = (f16*)((char*)d_ws + OFF_A);
    f16* Alo = Ahi + (size_t)MROWS * DDIM;
    f16* Bhi = Alo + (size_t)MROWS * DDIM;
    f16* Blo = Bhi + (size_t)KCODES * DDIM;

    hipLaunchKernelGGL(init_packed, dim3(32), dim3(256), 0, stream, packed);
    hipLaunchKernelGGL(prep_x,  dim3(MROWS),  dim3(256), 0, stream, x,  Ahi, Alo);
    hipLaunchKernelGGL(prep_cb, dim3(KCODES), dim3(256), 0, stream, cb, Bhi, Blo, csq);
    hipLaunchKernelGGL(vq_gemm, dim3(64, 64), dim3(256), 0, stream,
                       Ahi, Alo, Bhi, Blo, csq, packed);
    hipLaunchKernelGGL(vq_gather, dim3(MROWS), dim3(256), 0, stream, packed, emb, pe, out);
  } else {
    hipLaunchKernelGGL(vq_fallback, dim3(MROWS), dim3(256), 0, stream, x, cb, emb, pe, out);
  }
}